// Round 16
// baseline (642.356 us; speedup 1.0000x reference)
//
#include <hip/hip_runtime.h>
#include <math.h>

#define NN 100000
#define EE 500000
#define NNB  1563            // 64-node blocks (qkvpb/node)
#define NFB  3125            // 32-node blocks (final); 32*3125 = 100000 exactly

typedef __attribute__((ext_vector_type(8))) short short8;
typedef __attribute__((ext_vector_type(4))) float f32x4;
#define Z4 (f32x4){0,0,0,0}

#define C16(row, ch) (((row)<<4) + ((ch) ^ ((row)&7)))
#define E16(row, col) ((C16((row),(col)>>3)<<3) + ((col)&7))

__device__ __forceinline__ f32x4 mfma16(short8 a, short8 b, f32x4 c){
    return __builtin_amdgcn_mfma_f32_16x16x32_bf16(a, b, c, 0, 0, 0);
}
__device__ __forceinline__ short f2bf(float f){
    union { float f; unsigned u; } v; v.f = f;
    unsigned r = v.u + 0x7fffu + ((v.u >> 16) & 1u);
    return (short)(r >> 16);
}
__device__ __forceinline__ float bf2f(short s){
    union { unsigned u; float f; } v; v.u = ((unsigned)(unsigned short)s) << 16;
    return v.f;
}
__device__ __forceinline__ short8 bfrag(const short* __restrict__ W, int K, int ct, int ks, int lane){
    return *(const short8*)(W + (long)(ct*16 + (lane&15))*K + ks*32 + (lane>>4)*8);
}

// ---------------- prep: bf16 weights ----------------
__global__ __launch_bounds__(256) void prep_kernel(
    const float* __restrict__ q_w, const float* __restrict__ k_w,
    const float* __restrict__ v_w, const float* __restrict__ out_w,
    const float* __restrict__ sp_w, const float* __restrict__ amp_w,
    const float* __restrict__ ph_w, short* __restrict__ dst)
{
    int i = blockIdx.x*256 + threadIdx.x;   // 90112
    float v;
    if      (i < 16384) v = q_w[i];
    else if (i < 32768) v = k_w[i-16384];
    else if (i < 49152) v = v_w[i-32768];
    else if (i < 65536) v = out_w[i-49152];
    else if (i < 81920) v = sp_w[i-65536];
    else if (i < 86016) v = amp_w[i-81920];
    else                v = ph_w[i-86016];
    dst[i] = f2bf(v);
}

// ---------------- combined weights: Wc[kk] = meas_w[kk] @ ent_w_half ----------------
__global__ __launch_bounds__(256) void combine_kernel(
    const float* __restrict__ ent_w, const float* __restrict__ meas_w,
    short* __restrict__ wCi, short* __restrict__ wCj)
{
    const int b = blockIdx.x;          // 512
    const int kk = b >> 7, half = (b >> 6) & 1, ot = (b >> 3) & 7, ct = b & 7;
    const int tid = threadIdx.x;
    const int o = ot*16 + (tid >> 4);
    const int c = ct*32 + (tid & 15)*2;
    const float* mrow  = meas_w + ((long)(kk*128 + o) << 7);
    const float* wbase = ent_w + (long)(half*128)*256 + c;
    float a0 = 0.f, a1 = 0.f;
    #pragma unroll 8
    for (int k = 0; k < 128; k++){
        float m = mrow[k];
        float2 wv = *(const float2*)(wbase + (long)k*256);
        a0 = fmaf(m, wv.x, a0);
        a1 = fmaf(m, wv.y, a1);
    }
    short* dst = (half ? wCj : wCi) + (long)kk*32768 + o*256 + c;
    dst[0] = f2bf(a0); dst[1] = f2bf(a1);
}
__global__ __launch_bounds__(256) void combine_bias_kernel(
    const float* __restrict__ meas_w, const float* __restrict__ ent_b,
    const float* __restrict__ meas_b,
    float* __restrict__ bci, float* __restrict__ bcj)
{
    int id = blockIdx.x*256 + threadIdx.x;  // 1024
    int kk = id >> 8, half = (id >> 7) & 1, o = id & 127;
    const float* mrow = meas_w + ((long)(kk*128 + o) << 7);
    const float* eb = ent_b + half*128;
    float a = meas_b[kk*128 + o];
    #pragma unroll 8
    for (int k = 0; k < 128; k++) a = fmaf(mrow[k], eb[k], a);
    (half ? bcj : bci)[kk*128 + o] = a;
}

// ---------------- counting sort by tgt (src list only) ----------------
__global__ __launch_bounds__(256) void hist_kernel(const int* __restrict__ eidx, int* __restrict__ hist){
    int i = blockIdx.x*256 + threadIdx.x;
    if (i < EE) atomicAdd(&hist[eidx[EE+i]], 1);
}
__global__ __launch_bounds__(512) void scanA_kernel(const int* __restrict__ hist,
                                                    int* __restrict__ scanv, int* __restrict__ bsum){
    __shared__ int s[512];
    const int tid = threadIdx.x;
    const int i = blockIdx.x*512 + tid;
    int v = hist[i];
    s[tid] = v;
    __syncthreads();
    #pragma unroll
    for (int d=1; d<512; d<<=1){
        int t = (tid>=d) ? s[tid-d] : 0;
        __syncthreads();
        s[tid] += t;
        __syncthreads();
    }
    scanv[i] = s[tid] - v;
    if (tid==511) bsum[blockIdx.x] = s[511];
}
__global__ __launch_bounds__(256) void scanB_kernel(const int* __restrict__ bsum, int* __restrict__ boff){
    __shared__ int s[256];
    const int tid = threadIdx.x;
    int v = (tid<196) ? bsum[tid] : 0;
    s[tid] = v;
    __syncthreads();
    #pragma unroll
    for (int d=1; d<256; d<<=1){
        int t = (tid>=d) ? s[tid-d] : 0;
        __syncthreads();
        s[tid] += t;
        __syncthreads();
    }
    if (tid<196) boff[tid] = s[tid] - v;
}
__global__ __launch_bounds__(256) void scatter_kernel(const int* __restrict__ eidx,
    const int* __restrict__ scanv, const int* __restrict__ boff, int* __restrict__ cnt,
    int* __restrict__ sSrc)
{
    int i = blockIdx.x*256 + threadIdx.x;
    if (i >= EE) return;
    int t = eidx[EE+i], sv = eidx[i];
    int r = atomicAdd(&cnt[t], 1);
    int pos = scanv[t] + boff[t>>9] + r;
    sSrc[pos] = sv;
}

// ---------------- Stage 1: node prep (proven) ----------------
__global__ __launch_bounds__(512) void node_kernel(
    const float* __restrict__ x,
    const short* __restrict__ wSP, const float* __restrict__ sp_b,
    const float* __restrict__ ln1_g, const float* __restrict__ ln1_b,
    const float* __restrict__ pg,
    const short* __restrict__ wA, const float* __restrict__ amp_b,
    const short* __restrict__ wP, const float* __restrict__ ph_b,
    short* __restrict__ qfb)
{
    __shared__ short xb[64*128];
    __shared__ float yb[64*132];
    __shared__ short qsb[64*128];
    __shared__ float pgs[64];

    const int tid = threadIdx.x;
    const int lane = tid & 63;
    const int w    = tid >> 6;
    const int l15  = lane & 15;
    const int lj   = (lane >> 4) << 2;
    const int n0   = blockIdx.x * 64;

    if (tid < 64){
        float s = 0.f;
        #pragma unroll
        for (int r=0;r<8;r++) s += pg[r*64 + tid];
        pgs[tid] = s;
    }
    for (int t = tid; t < 1024; t += 512){
        int e = t >> 4, c8 = t & 15;
        int n = n0 + e; if (n >= NN) n = NN-1;
        const float4* xg = (const float4*)(x + (long)n*128 + c8*8);
        float4 a = xg[0], b = xg[1];
        short8 sv;
        sv[0]=f2bf(a.x); sv[1]=f2bf(a.y); sv[2]=f2bf(a.z); sv[3]=f2bf(a.w);
        sv[4]=f2bf(b.x); sv[5]=f2bf(b.y); sv[6]=f2bf(b.z); sv[7]=f2bf(b.w);
        ((short8*)xb)[C16(e, c8)] = sv;
    }
    __syncthreads();

    const short8* xbv = (const short8*)xb;
    const int col = (w<<4) + l15;

    {
        f32x4 acc[4];
        #pragma unroll
        for (int r=0;r<4;r++) acc[r]=Z4;
        #pragma unroll
        for (int ks=0; ks<4; ks++){
            short8 bw = bfrag(wSP,128,w,ks,lane);
            #pragma unroll
            for (int r=0;r<4;r++){
                int row = r*16+l15;
                acc[r] = mfma16(xbv[(row<<4) + (((ks<<2)+(lane>>4)) ^ (row&7))], bw, acc[r]);
            }
        }
        float bias = sp_b[col];
        #pragma unroll
        for (int r=0;r<4;r++){
            #pragma unroll
            for (int j=0;j<4;j++)
                yb[(r*16+lj+j)*132 + col] = acc[r][j] + bias;
        }
    }
    __syncthreads();

    {
        const int row = tid >> 3, cs = tid & 7;
        float v[16];
        float s = 0.f, sq = 0.f;
        #pragma unroll
        for (int i=0;i<16;i++){
            v[i] = yb[row*132 + cs*16 + i];
            s += v[i]; sq += v[i]*v[i];
        }
        #pragma unroll
        for (int m=1;m<8;m<<=1){ s += __shfl_xor(s,m); sq += __shfl_xor(sq,m); }
        float mean = s*(1.0f/128.0f);
        float rstd = rsqrtf(sq*(1.0f/128.0f) - mean*mean + 1e-5f);
        short8 s0, s1;
        #pragma unroll
        for (int i=0;i<16;i++){
            int c = cs*16 + i;
            float q = tanhf((v[i]-mean)*rstd*ln1_g[c] + ln1_b[c]);
            if (i<8) s0[i] = f2bf(q); else s1[i-8] = f2bf(q);
        }
        ((short8*)qsb)[C16(row, cs*2  )] = s0;
        ((short8*)qsb)[C16(row, cs*2+1)] = s1;
    }
    __syncthreads();

    {
        const short8* qv = (const short8*)qsb;
        const int isPh = w >> 2;
        const int ct   = w & 3;
        f32x4 a4[4];
        #pragma unroll
        for (int r=0;r<4;r++) a4[r]=Z4;
        #pragma unroll
        for (int ks=0; ks<2; ks++){
            short8 bw = bfrag(isPh ? wP : wA, 64, ct, ks, lane);
            #pragma unroll
            for (int r=0;r<4;r++){
                int row = r*16+l15;
                int ch = isPh*8 + (ks<<2)+(lane>>4);
                a4[r] = mfma16(qv[(row<<4) + (ch ^ (row&7))], bw, a4[r]);
            }
        }
        const int oc = ct*16 + l15;
        float bs = isPh ? ph_b[oc] : amp_b[oc];
        #pragma unroll
        for (int r=0;r<4;r++){
            #pragma unroll
            for (int j=0;j<4;j++){
                float vv = a4[r][j] + bs;
                float ov = isPh ? tanhf(vv)*3.14159265358979323846f
                                : 1.0f/(1.0f+expf(-vv));
                yb[(r*16+lj+j)*132 + isPh*64 + oc] = ov;
            }
        }
    }
    __syncthreads();

    {
        const int row = tid >> 3, cs = tid & 7;
        const int n = n0 + row;
        short8 outc, outs;
        #pragma unroll
        for (int i=0;i<8;i++){
            int c = cs*8 + i;
            float amp  = yb[row*132 + c];
            float ph   = yb[row*132 + 64 + c];
            float real = bf2f(qsb[E16(row, c)]);
            float ang  = ph + real*pgs[c];
            outc[i] = f2bf(amp * cosf(ang));
            outs[i] = f2bf(amp * sinf(ang));
        }
        if (n < NN){
            *(short8*)(qfb + (long)n*128 + cs*8)      = outc;
            *(short8*)(qfb + (long)n*128 + 64 + cs*8) = outs;
        }
    }
}

// ---------------- node GEMMs -> packed knvp[n][512] = kn | vn | pb | qf ----------------
__global__ __launch_bounds__(512) void qkvpb_kernel(
    const short* __restrict__ qfb,
    const short* __restrict__ wK, const float* __restrict__ k_b,
    const short* __restrict__ wV, const float* __restrict__ v_b,
    const short* __restrict__ wCi, const short* __restrict__ wCj,
    short* __restrict__ knvp)
{
    __shared__ short a1[64*128];
    const int tid=threadIdx.x, lane=tid&63, w=tid>>6;
    const int l15=lane&15, lh=lane>>4, lj=lh<<2;
    const long n0=(long)blockIdx.x*64;
    for (int t=tid;t<1024;t+=512){
        int e=t>>4,c8=t&15;
        short8 val = ((const short8*)(qfb+(n0+e)*128))[c8];
        ((short8*)a1)[C16(e,c8)] = val;
        *(short8*)(knvp + (n0+e)*512 + 384 + c8*8) = val;   // qf copy into pack
    }
    __syncthreads();
    short8 A[4][4];
    #pragma unroll
    for (int rt=0;rt<4;rt++)
        #pragma unroll
        for (int ks=0;ks<4;ks++)
            A[rt][ks] = ((const short8*)a1)[C16(rt*16+l15, (ks<<2)+lh)];
    const int col = (w<<4)+l15;

    // K
    {
        f32x4 acc[4];
        #pragma unroll
        for (int rt=0;rt<4;rt++) acc[rt]=Z4;
        #pragma unroll
        for (int ks=0;ks<4;ks++){
            short8 b = *(const short8*)(wK + (long)col*128 + ks*32 + lh*8);
            #pragma unroll
            for (int rt=0;rt<4;rt++) acc[rt]=mfma16(A[rt][ks],b,acc[rt]);
        }
        float bias=k_b[col];
        #pragma unroll
        for (int rt=0;rt<4;rt++)
            #pragma unroll
            for (int j=0;j<4;j++)
                knvp[(n0+rt*16+lj+j)*512 + col]=f2bf(acc[rt][j]+bias);
    }
    // V
    {
        f32x4 acc[4];
        #pragma unroll
        for (int rt=0;rt<4;rt++) acc[rt]=Z4;
        #pragma unroll
        for (int ks=0;ks<4;ks++){
            short8 b = *(const short8*)(wV + (long)col*128 + ks*32 + lh*8);
            #pragma unroll
            for (int rt=0;rt<4;rt++) acc[rt]=mfma16(A[rt][ks],b,acc[rt]);
        }
        float bias=v_b[col];
        #pragma unroll
        for (int rt=0;rt<4;rt++)
            #pragma unroll
            for (int j=0;j<4;j++)
                knvp[(n0+rt*16+lj+j)*512 + 128 + col]=f2bf(acc[rt][j]+bias);
    }
    // PB = sum_kk Bi ⊙ Bj  (b-slices of wCi/wCj: cols 128:256)
    {
        f32x4 pbacc[4];
        #pragma unroll
        for (int rt=0;rt<4;rt++) pbacc[rt]=Z4;
        #pragma unroll 1
        for (int kk=0;kk<4;kk++){
            short8 bi[4], bj[4];
            #pragma unroll
            for (int ks=0;ks<4;ks++){
                bi[ks] = *(const short8*)(wCi + (long)kk*32768 + (long)col*256 + 128 + ks*32 + lh*8);
                bj[ks] = *(const short8*)(wCj + (long)kk*32768 + (long)col*256 + 128 + ks*32 + lh*8);
            }
            #pragma unroll
            for (int rt=0;rt<4;rt++){
                f32x4 ai=Z4, aj=Z4;
                #pragma unroll
                for (int ks=0;ks<4;ks++){
                    ai = mfma16(A[rt][ks], bi[ks], ai);
                    aj = mfma16(A[rt][ks], bj[ks], aj);
                }
                #pragma unroll
                for (int j=0;j<4;j++) pbacc[rt][j] += ai[j]*aj[j];
            }
        }
        #pragma unroll
        for (int rt=0;rt<4;rt++)
            #pragma unroll
            for (int j=0;j<4;j++)
                knvp[(n0+rt*16+lj+j)*512 + 256 + col]=f2bf(pbacc[rt][j]);
    }
}

// ---------------- final: 32 nodes/block, 512 threads / 8 waves ----------------
// Wave w: walk rows 4w..4w+3; GEMM col-tile ct=w. LDS 49 KB.
__global__ __launch_bounds__(512) void final_kernel(
    const short* __restrict__ qfb, const short* __restrict__ knvp,
    const int* __restrict__ sSrc, const int* __restrict__ hist,
    const int* __restrict__ scanv, const int* __restrict__ boff,
    const short* __restrict__ wQ, const float* __restrict__ q_b,
    const short* __restrict__ wCi, const short* __restrict__ wCj,
    const float* __restrict__ bci, const float* __restrict__ bcj,
    const short* __restrict__ wO, const float* __restrict__ out_b,
    const float* __restrict__ g2, const float* __restrict__ b2,
    float* __restrict__ outp)
{
    __shared__ __align__(16) char smem[49152];
    __shared__ int degs[32];
    short* a1   = (short*)smem;            // 8 KB qf tile (swz); later msgb overlay
    short* qnl  = (short*)(smem + 8192);   // 8 KB qn [32][128] linear
    float* AQM  = (float*)(smem + 16384);  // 16 KB f32 [32][128]
    short* Sbf  = (short*)(smem + 32768);  // 8 KB bf16 swz [32][128]
    short* PBbf = (short*)(smem + 40960);  // 8 KB bf16 plain [32][128]
    float* yb   = (float*)(smem + 8192);   // 16 KB overlay (qnl+AQM) for OUT result

    const int tid=threadIdx.x, lane=tid&63, w=tid>>6;   // w = 0..7
    const int l15=lane&15, lh=lane>>4, lj=lh<<2;
    const long n0=(long)blockIdx.x*32;
    const int col = (w<<4) + l15;          // this wave's 16 output cols

    if (tid < 32) degs[tid] = hist[n0+tid];
    if (tid < 512){
        int t = tid;
        int e=t>>4,c8=t&15;
        ((short8*)a1)[C16(e,c8)] = ((const short8*)(qfb+(n0+e)*128))[c8];
    }
    __syncthreads();                                       // B1

    // ---- qf A-frags (reg-cached) + qn GEMM (ct = w) ----
    short8 FQ[2][4];
    #pragma unroll
    for (int rt=0;rt<2;rt++)
        #pragma unroll
        for (int ks=0;ks<4;ks++)
            FQ[rt][ks] = ((const short8*)a1)[C16(rt*16+l15,(ks<<2)+lh)];
    {
        f32x4 acc[2]; acc[0]=Z4; acc[1]=Z4;
        #pragma unroll
        for (int ks=0;ks<4;ks++){
            short8 b = *(const short8*)(wQ + (long)col*128 + ks*32 + lh*8);
            acc[0]=mfma16(FQ[0][ks],b,acc[0]);
            acc[1]=mfma16(FQ[1][ks],b,acc[1]);
        }
        float bias=q_b[col];
        #pragma unroll
        for (int rt=0;rt<2;rt++)
            #pragma unroll
            for (int j=0;j<4;j++)
                qnl[(rt*16+lj+j)*128 + col] = f2bf(acc[rt][j]+bias);
    }
    __syncthreads();                                       // B2

    // ---- CSR edge walk: wave w owns rows 4w..4w+3; 4 edges in flight + 1-ahead prefetch ----
    {
        const float sc = 0.17677669529663688f;
        const int g  = lane >> 4;          // edge slot 0..3
        const int cl = (lane & 15) * 8;    // this lane covers cols cl..cl+7
        #pragma unroll 1
        for (int nn=0; nn<4; nn++){
            const int row = w*4 + nn;
            const long n = n0 + row;
            const int rp0 = scanv[n] + boff[n>>9];
            const int dg  = degs[row];
            float q8[8];
            {
                short8 qv = *(const short8*)(qnl + row*128 + cl);
                #pragma unroll
                for (int i=0;i<8;i++) q8[i]=bf2f(qv[i]);
            }
            float raqm[8], rs[8], rpb[8];
            #pragma unroll
            for (int i=0;i<8;i++){ raqm[i]=0.f; rs[i]=0.f; rpb[i]=0.f; }

            // prologue: load group 0
            bool vCur = (g < dg);
            int  sCur = vCur ? sSrc[rp0+g] : 0;
            const short* bCur = knvp + (long)sCur*512;
            short8 k8 = *(const short8*)(bCur + cl);
            short8 v8 = *(const short8*)(bCur + 128 + cl);
            short8 p8 = *(const short8*)(bCur + 256 + cl);
            short8 f8 = *(const short8*)(bCur + 384 + cl);

            #pragma unroll 1
            for (int e=0; e<dg; e+=4){
                const int en = e + 4 + g;
                const bool vN = (en < dg);
                const int  sN = vN ? sSrc[rp0+en] : 0;
                const short* bN = knvp + (long)sN*512;
                short8 kN = *(const short8*)(bN + cl);
                short8 vN8= *(const short8*)(bN + 128 + cl);
                short8 pN = *(const short8*)(bN + 256 + cl);
                short8 fN = *(const short8*)(bN + 384 + cl);

                float p = 0.f;
                #pragma unroll
                for (int i=0;i<8;i++) p += q8[i]*bf2f(k8[i]);
                p += __shfl_xor(p,1); p += __shfl_xor(p,2);   // head sum (4 lanes/head)
                p *= sc;
                float mx = fmaxf(p, __shfl_xor(p,4));
                mx = fmaxf(mx, __shfl_xor(mx,8));             // max over 4 heads
                float eh = expf(p - mx);
                float den = eh;
                den += __shfl_xor(den,4); den += __shfl_xor(den,8);
                float wgt = vCur ? (eh/den) : 0.f;
                float mval = vCur ? 1.f : 0.f;
                #pragma unroll
                for (int i=0;i<8;i++){
                    raqm[i] += wgt  * bf2f(v8[i]);
                    rs[i]   += mval * bf2f(f8[i]);
                    rpb[i]  += mval * bf2f(p8[i]);
                }
                k8=kN; v8=vN8; p8=pN; f8=fN; vCur=vN;
            }
            // combine the 4 edge-slot groups
            #pragma unroll
            for (int i=0;i<8;i++){
                raqm[i] += __shfl_xor(raqm[i],16); raqm[i] += __shfl_xor(raqm[i],32);
                rs[i]   += __shfl_xor(rs[i],16);   rs[i]   += __shfl_xor(rs[i],32);
                rpb[i]  += __shfl_xor(rpb[i],16);  rpb[i]  += __shfl_xor(rpb[i],32);
            }
            if (lane < 16){
                short8 sv, pv;
                #pragma unroll
                for (int i=0;i<8;i++){
                    AQM[row*128 + cl + i] = raqm[i];
                    sv[i] = f2bf(rs[i]);
                    pv[i] = f2bf(rpb[i]);
                }
                ((short8*)Sbf)[C16(row, lane&15)] = sv;
                *(short8*)(PBbf + row*128 + cl) = pv;
            }
        }
    }
    __syncthreads();                                       // B3

    short8 FS[2][4];
    #pragma unroll
    for (int rt=0;rt<2;rt++)
        #pragma unroll
        for (int ks=0;ks<4;ks++)
            FS[rt][ks] = ((const short8*)Sbf)[C16(rt*16+l15,(ks<<2)+lh)];

    // ---- cross GEMMs (ct = w) ----
    f32x4 tt[2], cr[2];
    tt[0]=Z4; tt[1]=Z4; cr[0]=Z4; cr[1]=Z4;
    #pragma unroll 1
    for (int kk=0;kk<4;kk++){
        const long wbase = (long)kk*32768 + (long)col*256;
        short8 Bia[4],Bja[4],Bib[4],Bjb[4];
        #pragma unroll
        for (int ks=0;ks<4;ks++){
            Bia[ks] = *(const short8*)(wCi + wbase + ks*32 + lh*8);
            Bja[ks] = *(const short8*)(wCj + wbase + ks*32 + lh*8);
            Bib[ks] = *(const short8*)(wCi + wbase + 128 + ks*32 + lh*8);
            Bjb[ks] = *(const short8*)(wCj + wbase + 128 + ks*32 + lh*8);
        }
        f32x4 ai[2],aj[2],sbi[2],sbj[2];
        #pragma unroll
        for (int rt=0;rt<2;rt++){ ai[rt]=Z4; aj[rt]=Z4; sbi[rt]=Z4; sbj[rt]=Z4; }
        #pragma unroll
        for (int ks=0;ks<4;ks++){
            #pragma unroll
            for (int rt=0;rt<2;rt++){
                ai[rt]  = mfma16(FQ[rt][ks], Bia[ks], ai[rt]);
                aj[rt]  = mfma16(FQ[rt][ks], Bja[ks], aj[rt]);
                sbi[rt] = mfma16(FS[rt][ks], Bib[ks], sbi[rt]);
                sbj[rt] = mfma16(FS[rt][ks], Bjb[ks], sbj[rt]);
            }
        }
        float ci_ = bci[kk*128+col], cj_ = bcj[kk*128+col];
        #pragma unroll
        for (int rt=0;rt<2;rt++){
            #pragma unroll
            for (int j=0;j<4;j++){
                float AI = ai[rt][j]+ci_, AJ = aj[rt][j]+cj_;
                tt[rt][j] += AI*AJ;
                cr[rt][j] += AI*sbj[rt][j] + sbi[rt][j]*AJ;
            }
        }
    }
    // ---- assemble msum, write msgb (over a1; a1 unread since FQ load) ----
    short* msgb = a1;
    #pragma unroll
    for (int rt=0;rt<2;rt++){
        #pragma unroll
        for (int j=0;j<4;j++){
            int row = rt*16+lj+j;
            float ms = AQM[row*128 + col]
                     + 0.25f*((float)degs[row]*tt[rt][j] + cr[rt][j]
                              + bf2f(PBbf[row*128 + col]));
            msgb[(C16(row, col>>3)<<3) + (col&7)] = f2bf(ms);
        }
    }
    __syncthreads();                                       // B4

    // ---- OUT GEMM -> yb (overlays qnl+AQM; both dead) ----
    short8 FM[2][4];
    #pragma unroll
    for (int rt=0;rt<2;rt++)
        #pragma unroll
        for (int ks=0;ks<4;ks++)
            FM[rt][ks] = ((const short8*)msgb)[C16(rt*16+l15,(ks<<2)+lh)];
    {
        f32x4 ao[2]; ao[0]=Z4; ao[1]=Z4;
        #pragma unroll
        for (int ks=0;ks<4;ks++){
            short8 b = *(const short8*)(wO + (long)col*128 + ks*32 + lh*8);
            ao[0]=mfma16(FM[0][ks],b,ao[0]);
            ao[1]=mfma16(FM[1][ks],b,ao[1]);
        }
        float ob = out_b[col];
        #pragma unroll
        for (int rt=0;rt<2;rt++)
            #pragma unroll
            for (int j=0;j<4;j++){
                int row = rt*16+lj+j;
                yb[(row<<7) + (col ^ (row&31))] = ao[rt][j] + (float)degs[row]*ob;
            }
    }
    __syncthreads();                                       // B5

    // ---- LN + exact gelu (16 threads/row, 8 cols each) ----
    {
        const int row=tid>>4, cs=tid&15;
        const long n=n0+row;
        float v[8]; float sum=0.f, sq=0.f;
        #pragma unroll
        for (int i=0;i<8;i++){
            v[i]=yb[(row<<7)+((cs*8+i)^(row&31))];
            sum+=v[i]; sq+=v[i]*v[i];
        }
        #pragma unroll
        for (int m=1;m<16;m<<=1){ sum+=__shfl_xor(sum,m); sq+=__shfl_xor(sq,m); }
        float mean=sum*(1.0f/128.0f);
        float rstd=rsqrtf(sq*(1.0f/128.0f)-mean*mean+1e-5f);
        float o[8];
        #pragma unroll
        for (int i=0;i<8;i++){
            int c=cs*8+i;
            float y=(v[i]-mean)*rstd*g2[c]+b2[c];
            o[i]=0.5f*y*(1.0f+erff(y*0.70710678118f));
        }
        float* dst = outp + n*128 + cs*8;
        ((float4*)dst)[0] = (float4){o[0],o[1],o[2],o[3]};
        ((float4*)dst)[1] = (float4){o[4],o[5],o[6],o[7]};
    }
}

extern "C" void kernel_launch(void* const* d_in, const int* in_sizes, int n_in,
                              void* d_out, int out_size, void* d_ws, size_t ws_size,
                              hipStream_t stream)
{
    const float* x      = (const float*)d_in[0];
    const int*   eidx   = (const int*)  d_in[1];
    const float* sp_w   = (const float*)d_in[2];
    const float* sp_b   = (const float*)d_in[3];
    const float* ln1_g  = (const float*)d_in[4];
    const float* ln1_b  = (const float*)d_in[5];
    const float* pg     = (const float*)d_in[6];
    const float* amp_w  = (const float*)d_in[7];
    const float* amp_b  = (const float*)d_in[8];
    const float* ph_w   = (const float*)d_in[9];
    const float* ph_b   = (const float*)d_in[10];
    const float* ent_w  = (const float*)d_in[11];
    const float* ent_b  = (const float*)d_in[12];
    const float* q_w    = (const float*)d_in[13];
    const float* q_b    = (const float*)d_in[14];
    const float* k_w    = (const float*)d_in[15];
    const float* k_b    = (const float*)d_in[16];
    const float* v_w    = (const float*)d_in[17];
    const float* v_b    = (const float*)d_in[18];
    const float* meas_w = (const float*)d_in[19];
    const float* meas_b = (const float*)d_in[20];
    const float* out_w  = (const float*)d_in[21];
    const float* out_b  = (const float*)d_in[22];
    const float* ln2_g  = (const float*)d_in[23];
    const float* ln2_b  = (const float*)d_in[24];

    char* wsb = (char*)d_ws;
    short* qfb  = (short*)(wsb + 0);               //  25,608,192
    short* knvp = (short*)(wsb + 25608192);        // 102,432,768
    short* wAll = (short*)(wsb + 128040960);       //     180,224
    short* wCi  = (short*)(wsb + 128221184);       //     262,144
    short* wCj  = (short*)(wsb + 128483328);       //     262,144
    float* bci  = (float*)(wsb + 128745472);       //       2,048
    float* bcj  = (float*)(wsb + 128747520);       //       2,048
    int* hist   = (int*)(wsb + 128749568);         //     401,408
    int* cnt    = (int*)(wsb + 129150976);         //     401,408
    int* scanv  = (int*)(wsb + 129552384);         //     401,408
    int* bsum   = (int*)(wsb + 129953792);         //       1,024
    int* boff   = (int*)(wsb + 129954816);         //       1,024
    int* sSrc   = (int*)(wsb + 129955840);         //   2,000,000 -> 131,955,840 total

    if (ws_size < 132000000ull) return;            // diagnostic guard

    short* wQ  = wAll;
    short* wK  = wAll + 16384;
    short* wV  = wAll + 32768;
    short* wO  = wAll + 49152;
    short* wSP = wAll + 65536;
    short* wA  = wAll + 81920;
    short* wP  = wAll + 86016;

    hipMemsetAsync(hist, 0, 401408, stream);
    hipMemsetAsync(cnt,  0, 401408, stream);

    prep_kernel<<<352, 256, 0, stream>>>(q_w, k_w, v_w, out_w, sp_w, amp_w, ph_w, wAll);
    combine_kernel<<<512, 256, 0, stream>>>(ent_w, meas_w, wCi, wCj);
    combine_bias_kernel<<<4, 256, 0, stream>>>(meas_w, ent_b, meas_b, bci, bcj);
    node_kernel<<<NNB, 512, 0, stream>>>(x, wSP, sp_b, ln1_g, ln1_b, pg,
                                         wA, amp_b, wP, ph_b, qfb);
    hist_kernel<<<(EE+255)/256, 256, 0, stream>>>(eidx, hist);
    scanA_kernel<<<196, 512, 0, stream>>>(hist, scanv, bsum);
    scanB_kernel<<<1, 256, 0, stream>>>(bsum, boff);
    scatter_kernel<<<(EE+255)/256, 256, 0, stream>>>(eidx, scanv, boff, cnt, sSrc);
    qkvpb_kernel<<<NNB, 512, 0, stream>>>(qfb, wK, k_b, wV, v_b, wCi, wCj, knvp);
    final_kernel<<<NFB, 512, 0, stream>>>(qfb, knvp, sSrc, hist, scanv, boff,
                                          wQ, q_b, wCi, wCj, bci, bcj, wO, out_b,
                                          ln2_g, ln2_b, (float*)d_out);
}

// Round 17
// 587.912 us; speedup vs baseline: 1.0926x; 1.0926x over previous
//
#include <hip/hip_runtime.h>
#include <math.h>

#define NN 100000
#define EE 500000
#define NNB  1563            // 64-node blocks (qkvpb/node)
#define NFB  3125            // 32-node blocks (final); 32*3125 = 100000 exactly

typedef __attribute__((ext_vector_type(8))) short short8;
typedef __attribute__((ext_vector_type(4))) float f32x4;
#define Z4 (f32x4){0,0,0,0}

#define C16(row, ch) (((row)<<4) + ((ch) ^ ((row)&7)))
#define E16(row, col) ((C16((row),(col)>>3)<<3) + ((col)&7))

__device__ __forceinline__ f32x4 mfma16(short8 a, short8 b, f32x4 c){
    return __builtin_amdgcn_mfma_f32_16x16x32_bf16(a, b, c, 0, 0, 0);
}
__device__ __forceinline__ short f2bf(float f){
    union { float f; unsigned u; } v; v.f = f;
    unsigned r = v.u + 0x7fffu + ((v.u >> 16) & 1u);
    return (short)(r >> 16);
}
__device__ __forceinline__ float bf2f(short s){
    union { unsigned u; float f; } v; v.u = ((unsigned)(unsigned short)s) << 16;
    return v.f;
}
__device__ __forceinline__ short8 bfrag(const short* __restrict__ W, int K, int ct, int ks, int lane){
    return *(const short8*)(W + (long)(ct*16 + (lane&15))*K + ks*32 + (lane>>4)*8);
}

// ---------------- prep: bf16 weights ----------------
__global__ __launch_bounds__(256) void prep_kernel(
    const float* __restrict__ q_w, const float* __restrict__ k_w,
    const float* __restrict__ v_w, const float* __restrict__ out_w,
    const float* __restrict__ sp_w, const float* __restrict__ amp_w,
    const float* __restrict__ ph_w, short* __restrict__ dst)
{
    int i = blockIdx.x*256 + threadIdx.x;   // 90112
    float v;
    if      (i < 16384) v = q_w[i];
    else if (i < 32768) v = k_w[i-16384];
    else if (i < 49152) v = v_w[i-32768];
    else if (i < 65536) v = out_w[i-49152];
    else if (i < 81920) v = sp_w[i-65536];
    else if (i < 86016) v = amp_w[i-81920];
    else                v = ph_w[i-86016];
    dst[i] = f2bf(v);
}

// ---------------- combined weights: Wc[kk] = meas_w[kk] @ ent_w_half ----------------
__global__ __launch_bounds__(256) void combine_kernel(
    const float* __restrict__ ent_w, const float* __restrict__ meas_w,
    short* __restrict__ wCi, short* __restrict__ wCj)
{
    const int b = blockIdx.x;          // 512
    const int kk = b >> 7, half = (b >> 6) & 1, ot = (b >> 3) & 7, ct = b & 7;
    const int tid = threadIdx.x;
    const int o = ot*16 + (tid >> 4);
    const int c = ct*32 + (tid & 15)*2;
    const float* mrow  = meas_w + ((long)(kk*128 + o) << 7);
    const float* wbase = ent_w + (long)(half*128)*256 + c;
    float a0 = 0.f, a1 = 0.f;
    #pragma unroll 8
    for (int k = 0; k < 128; k++){
        float m = mrow[k];
        float2 wv = *(const float2*)(wbase + (long)k*256);
        a0 = fmaf(m, wv.x, a0);
        a1 = fmaf(m, wv.y, a1);
    }
    short* dst = (half ? wCj : wCi) + (long)kk*32768 + o*256 + c;
    dst[0] = f2bf(a0); dst[1] = f2bf(a1);
}
__global__ __launch_bounds__(256) void combine_bias_kernel(
    const float* __restrict__ meas_w, const float* __restrict__ ent_b,
    const float* __restrict__ meas_b,
    float* __restrict__ bci, float* __restrict__ bcj)
{
    int id = blockIdx.x*256 + threadIdx.x;  // 1024
    int kk = id >> 8, half = (id >> 7) & 1, o = id & 127;
    const float* mrow = meas_w + ((long)(kk*128 + o) << 7);
    const float* eb = ent_b + half*128;
    float a = meas_b[kk*128 + o];
    #pragma unroll 8
    for (int k = 0; k < 128; k++) a = fmaf(mrow[k], eb[k], a);
    (half ? bcj : bci)[kk*128 + o] = a;
}

// ---------------- counting sort by tgt (src list only) ----------------
__global__ __launch_bounds__(256) void hist_kernel(const int* __restrict__ eidx, int* __restrict__ hist){
    int i = blockIdx.x*256 + threadIdx.x;
    if (i < EE) atomicAdd(&hist[eidx[EE+i]], 1);
}
__global__ __launch_bounds__(512) void scanA_kernel(const int* __restrict__ hist,
                                                    int* __restrict__ scanv, int* __restrict__ bsum){
    __shared__ int s[512];
    const int tid = threadIdx.x;
    const int i = blockIdx.x*512 + tid;
    int v = hist[i];
    s[tid] = v;
    __syncthreads();
    #pragma unroll
    for (int d=1; d<512; d<<=1){
        int t = (tid>=d) ? s[tid-d] : 0;
        __syncthreads();
        s[tid] += t;
        __syncthreads();
    }
    scanv[i] = s[tid] - v;
    if (tid==511) bsum[blockIdx.x] = s[511];
}
__global__ __launch_bounds__(256) void scanB_kernel(const int* __restrict__ bsum, int* __restrict__ boff){
    __shared__ int s[256];
    const int tid = threadIdx.x;
    int v = (tid<196) ? bsum[tid] : 0;
    s[tid] = v;
    __syncthreads();
    #pragma unroll
    for (int d=1; d<256; d<<=1){
        int t = (tid>=d) ? s[tid-d] : 0;
        __syncthreads();
        s[tid] += t;
        __syncthreads();
    }
    if (tid<196) boff[tid] = s[tid] - v;
}
__global__ __launch_bounds__(256) void scatter_kernel(const int* __restrict__ eidx,
    const int* __restrict__ scanv, const int* __restrict__ boff, int* __restrict__ cnt,
    int* __restrict__ sSrc)
{
    int i = blockIdx.x*256 + threadIdx.x;
    if (i >= EE) return;
    int t = eidx[EE+i], sv = eidx[i];
    int r = atomicAdd(&cnt[t], 1);
    int pos = scanv[t] + boff[t>>9] + r;
    sSrc[pos] = sv;
}

// ---------------- Stage 1: node prep (proven) ----------------
__global__ __launch_bounds__(512) void node_kernel(
    const float* __restrict__ x,
    const short* __restrict__ wSP, const float* __restrict__ sp_b,
    const float* __restrict__ ln1_g, const float* __restrict__ ln1_b,
    const float* __restrict__ pg,
    const short* __restrict__ wA, const float* __restrict__ amp_b,
    const short* __restrict__ wP, const float* __restrict__ ph_b,
    short* __restrict__ qfb)
{
    __shared__ short xb[64*128];
    __shared__ float yb[64*132];
    __shared__ short qsb[64*128];
    __shared__ float pgs[64];

    const int tid = threadIdx.x;
    const int lane = tid & 63;
    const int w    = tid >> 6;
    const int l15  = lane & 15;
    const int lj   = (lane >> 4) << 2;
    const int n0   = blockIdx.x * 64;

    if (tid < 64){
        float s = 0.f;
        #pragma unroll
        for (int r=0;r<8;r++) s += pg[r*64 + tid];
        pgs[tid] = s;
    }
    for (int t = tid; t < 1024; t += 512){
        int e = t >> 4, c8 = t & 15;
        int n = n0 + e; if (n >= NN) n = NN-1;
        const float4* xg = (const float4*)(x + (long)n*128 + c8*8);
        float4 a = xg[0], b = xg[1];
        short8 sv;
        sv[0]=f2bf(a.x); sv[1]=f2bf(a.y); sv[2]=f2bf(a.z); sv[3]=f2bf(a.w);
        sv[4]=f2bf(b.x); sv[5]=f2bf(b.y); sv[6]=f2bf(b.z); sv[7]=f2bf(b.w);
        ((short8*)xb)[C16(e, c8)] = sv;
    }
    __syncthreads();

    const short8* xbv = (const short8*)xb;
    const int col = (w<<4) + l15;

    {
        f32x4 acc[4];
        #pragma unroll
        for (int r=0;r<4;r++) acc[r]=Z4;
        #pragma unroll
        for (int ks=0; ks<4; ks++){
            short8 bw = bfrag(wSP,128,w,ks,lane);
            #pragma unroll
            for (int r=0;r<4;r++){
                int row = r*16+l15;
                acc[r] = mfma16(xbv[(row<<4) + (((ks<<2)+(lane>>4)) ^ (row&7))], bw, acc[r]);
            }
        }
        float bias = sp_b[col];
        #pragma unroll
        for (int r=0;r<4;r++){
            #pragma unroll
            for (int j=0;j<4;j++)
                yb[(r*16+lj+j)*132 + col] = acc[r][j] + bias;
        }
    }
    __syncthreads();

    {
        const int row = tid >> 3, cs = tid & 7;
        float v[16];
        float s = 0.f, sq = 0.f;
        #pragma unroll
        for (int i=0;i<16;i++){
            v[i] = yb[row*132 + cs*16 + i];
            s += v[i]; sq += v[i]*v[i];
        }
        #pragma unroll
        for (int m=1;m<8;m<<=1){ s += __shfl_xor(s,m); sq += __shfl_xor(sq,m); }
        float mean = s*(1.0f/128.0f);
        float rstd = rsqrtf(sq*(1.0f/128.0f) - mean*mean + 1e-5f);
        short8 s0, s1;
        #pragma unroll
        for (int i=0;i<16;i++){
            int c = cs*16 + i;
            float q = tanhf((v[i]-mean)*rstd*ln1_g[c] + ln1_b[c]);
            if (i<8) s0[i] = f2bf(q); else s1[i-8] = f2bf(q);
        }
        ((short8*)qsb)[C16(row, cs*2  )] = s0;
        ((short8*)qsb)[C16(row, cs*2+1)] = s1;
    }
    __syncthreads();

    {
        const short8* qv = (const short8*)qsb;
        const int isPh = w >> 2;
        const int ct   = w & 3;
        f32x4 a4[4];
        #pragma unroll
        for (int r=0;r<4;r++) a4[r]=Z4;
        #pragma unroll
        for (int ks=0; ks<2; ks++){
            short8 bw = bfrag(isPh ? wP : wA, 64, ct, ks, lane);
            #pragma unroll
            for (int r=0;r<4;r++){
                int row = r*16+l15;
                int ch = isPh*8 + (ks<<2)+(lane>>4);
                a4[r] = mfma16(qv[(row<<4) + (ch ^ (row&7))], bw, a4[r]);
            }
        }
        const int oc = ct*16 + l15;
        float bs = isPh ? ph_b[oc] : amp_b[oc];
        #pragma unroll
        for (int r=0;r<4;r++){
            #pragma unroll
            for (int j=0;j<4;j++){
                float vv = a4[r][j] + bs;
                float ov = isPh ? tanhf(vv)*3.14159265358979323846f
                                : 1.0f/(1.0f+expf(-vv));
                yb[(r*16+lj+j)*132 + isPh*64 + oc] = ov;
            }
        }
    }
    __syncthreads();

    {
        const int row = tid >> 3, cs = tid & 7;
        const int n = n0 + row;
        short8 outc, outs;
        #pragma unroll
        for (int i=0;i<8;i++){
            int c = cs*8 + i;
            float amp  = yb[row*132 + c];
            float ph   = yb[row*132 + 64 + c];
            float real = bf2f(qsb[E16(row, c)]);
            float ang  = ph + real*pgs[c];
            outc[i] = f2bf(amp * cosf(ang));
            outs[i] = f2bf(amp * sinf(ang));
        }
        if (n < NN){
            *(short8*)(qfb + (long)n*128 + cs*8)      = outc;
            *(short8*)(qfb + (long)n*128 + 64 + cs*8) = outs;
        }
    }
}

// ---------------- node GEMMs -> packed knvp[n][512] = kn | vn | pb | qf ----------------
__global__ __launch_bounds__(512) void qkvpb_kernel(
    const short* __restrict__ qfb,
    const short* __restrict__ wK, const float* __restrict__ k_b,
    const short* __restrict__ wV, const float* __restrict__ v_b,
    const short* __restrict__ wCi, const short* __restrict__ wCj,
    short* __restrict__ knvp)
{
    __shared__ short a1[64*128];
    const int tid=threadIdx.x, lane=tid&63, w=tid>>6;
    const int l15=lane&15, lh=lane>>4, lj=lh<<2;
    const long n0=(long)blockIdx.x*64;
    for (int t=tid;t<1024;t+=512){
        int e=t>>4,c8=t&15;
        short8 val = ((const short8*)(qfb+(n0+e)*128))[c8];
        ((short8*)a1)[C16(e,c8)] = val;
        *(short8*)(knvp + (n0+e)*512 + 384 + c8*8) = val;   // qf copy into pack
    }
    __syncthreads();
    short8 A[4][4];
    #pragma unroll
    for (int rt=0;rt<4;rt++)
        #pragma unroll
        for (int ks=0;ks<4;ks++)
            A[rt][ks] = ((const short8*)a1)[C16(rt*16+l15, (ks<<2)+lh)];
    const int col = (w<<4)+l15;

    // K
    {
        f32x4 acc[4];
        #pragma unroll
        for (int rt=0;rt<4;rt++) acc[rt]=Z4;
        #pragma unroll
        for (int ks=0;ks<4;ks++){
            short8 b = *(const short8*)(wK + (long)col*128 + ks*32 + lh*8);
            #pragma unroll
            for (int rt=0;rt<4;rt++) acc[rt]=mfma16(A[rt][ks],b,acc[rt]);
        }
        float bias=k_b[col];
        #pragma unroll
        for (int rt=0;rt<4;rt++)
            #pragma unroll
            for (int j=0;j<4;j++)
                knvp[(n0+rt*16+lj+j)*512 + col]=f2bf(acc[rt][j]+bias);
    }
    // V
    {
        f32x4 acc[4];
        #pragma unroll
        for (int rt=0;rt<4;rt++) acc[rt]=Z4;
        #pragma unroll
        for (int ks=0;ks<4;ks++){
            short8 b = *(const short8*)(wV + (long)col*128 + ks*32 + lh*8);
            #pragma unroll
            for (int rt=0;rt<4;rt++) acc[rt]=mfma16(A[rt][ks],b,acc[rt]);
        }
        float bias=v_b[col];
        #pragma unroll
        for (int rt=0;rt<4;rt++)
            #pragma unroll
            for (int j=0;j<4;j++)
                knvp[(n0+rt*16+lj+j)*512 + 128 + col]=f2bf(acc[rt][j]+bias);
    }
    // PB = sum_kk Bi ⊙ Bj  (b-slices of wCi/wCj: cols 128:256)
    {
        f32x4 pbacc[4];
        #pragma unroll
        for (int rt=0;rt<4;rt++) pbacc[rt]=Z4;
        #pragma unroll 1
        for (int kk=0;kk<4;kk++){
            short8 bi[4], bj[4];
            #pragma unroll
            for (int ks=0;ks<4;ks++){
                bi[ks] = *(const short8*)(wCi + (long)kk*32768 + (long)col*256 + 128 + ks*32 + lh*8);
                bj[ks] = *(const short8*)(wCj + (long)kk*32768 + (long)col*256 + 128 + ks*32 + lh*8);
            }
            #pragma unroll
            for (int rt=0;rt<4;rt++){
                f32x4 ai=Z4, aj=Z4;
                #pragma unroll
                for (int ks=0;ks<4;ks++){
                    ai = mfma16(A[rt][ks], bi[ks], ai);
                    aj = mfma16(A[rt][ks], bj[ks], aj);
                }
                #pragma unroll
                for (int j=0;j<4;j++) pbacc[rt][j] += ai[j]*aj[j];
            }
        }
        #pragma unroll
        for (int rt=0;rt<4;rt++)
            #pragma unroll
            for (int j=0;j<4;j++)
                knvp[(n0+rt*16+lj+j)*512 + 256 + col]=f2bf(pbacc[rt][j]);
    }
}

// ---------------- final: 32 nodes/block, 256 threads; dual-row interleaved walk ----------------
__global__ __launch_bounds__(256) void final_kernel(
    const short* __restrict__ qfb, const short* __restrict__ knvp,
    const int* __restrict__ sSrc, const int* __restrict__ hist,
    const int* __restrict__ scanv, const int* __restrict__ boff,
    const short* __restrict__ wQ, const float* __restrict__ q_b,
    const short* __restrict__ wCi, const short* __restrict__ wCj,
    const float* __restrict__ bci, const float* __restrict__ bcj,
    const short* __restrict__ wO, const float* __restrict__ out_b,
    const float* __restrict__ g2, const float* __restrict__ b2,
    float* __restrict__ outp)
{
    __shared__ __align__(16) char smem[49152];
    __shared__ int degs[32];
    short* a1   = (short*)smem;            // 8 KB qf tile (swz); later msgb overlay
    short* qnl  = (short*)(smem + 8192);   // 8 KB qn [32][128] linear
    float* AQM  = (float*)(smem + 16384);  // 16 KB f32 [32][128]
    short* Sbf  = (short*)(smem + 32768);  // 8 KB bf16 swz [32][128]
    short* PBbf = (short*)(smem + 40960);  // 8 KB bf16 plain [32][128]
    float* yb   = (float*)(smem + 8192);   // 16 KB overlay (qnl+AQM) for OUT result

    const int tid=threadIdx.x, lane=tid&63, w=tid>>6;
    const int l15=lane&15, lh=lane>>4, lj=lh<<2;
    const long n0=(long)blockIdx.x*32;

    if (tid < 32) degs[tid] = hist[n0+tid];
    for (int t=tid;t<512;t+=256){
        int e=t>>4,c8=t&15;
        ((short8*)a1)[C16(e,c8)] = ((const short8*)(qfb+(n0+e)*128))[c8];
    }
    __syncthreads();                                       // B1

    // ---- qn GEMM (FQ frags loaded transiently; reloaded later for cross GEMMs) ----
    {
        short8 FQt[2][4];
        #pragma unroll
        for (int rt=0;rt<2;rt++)
            #pragma unroll
            for (int ks=0;ks<4;ks++)
                FQt[rt][ks] = ((const short8*)a1)[C16(rt*16+l15,(ks<<2)+lh)];
        #pragma unroll
        for (int ci=0; ci<2; ci++){
            const int col = (2*w+ci)*16 + l15;
            f32x4 acc[2]; acc[0]=Z4; acc[1]=Z4;
            #pragma unroll
            for (int ks=0;ks<4;ks++){
                short8 b = *(const short8*)(wQ + (long)col*128 + ks*32 + lh*8);
                acc[0]=mfma16(FQt[0][ks],b,acc[0]);
                acc[1]=mfma16(FQt[1][ks],b,acc[1]);
            }
            float bias=q_b[col];
            #pragma unroll
            for (int rt=0;rt<2;rt++)
                #pragma unroll
                for (int j=0;j<4;j++)
                    qnl[(rt*16+lj+j)*128 + col] = f2bf(acc[rt][j]+bias);
        }
    }
    __syncthreads();                                       // B2

    // ---- CSR edge walk: wave w owns rows 8w..8w+7, processed in PAIRS (2 chains in flight) ----
    {
        const float sc = 0.17677669529663688f;
        const int g  = lane >> 4;          // edge slot 0..3
        const int cl = (lane & 15) * 8;    // this lane covers cols cl..cl+7
        #pragma unroll 1
        for (int nn=0; nn<8; nn+=2){
            const int rowA = w*8 + nn, rowB = rowA + 1;
            const int rpA = scanv[n0+rowA] + boff[(n0+rowA)>>9];
            const int rpB = scanv[n0+rowB] + boff[(n0+rowB)>>9];
            const int dgA = degs[rowA], dgB = degs[rowB];
            float qA[8], qB[8];
            {
                short8 qa = *(const short8*)(qnl + rowA*128 + cl);
                short8 qb = *(const short8*)(qnl + rowB*128 + cl);
                #pragma unroll
                for (int i=0;i<8;i++){ qA[i]=bf2f(qa[i]); qB[i]=bf2f(qb[i]); }
            }
            float aA[8], sA[8], pA[8], aB[8], sB[8], pB[8];
            #pragma unroll
            for (int i=0;i<8;i++){ aA[i]=0;sA[i]=0;pA[i]=0; aB[i]=0;sB[i]=0;pB[i]=0; }

            const int itA = (dgA+3)>>2, itB = (dgB+3)>>2;
            const int itM = itA > itB ? itA : itB;
            #pragma unroll 1
            for (int it=0; it<itM; it++){
                const int eA = it*4 + g, eB = it*4 + g;
                const bool vA = (eA < dgA), vB = (eB < dgB);
                const int  nA = vA ? sSrc[rpA+eA] : 0;
                const int  nB = vB ? sSrc[rpB+eB] : 0;
                const short* bA = knvp + (long)nA*512;
                const short* bB = knvp + (long)nB*512;
                short8 kA8 = *(const short8*)(bA + cl);
                short8 vA8 = *(const short8*)(bA + 128 + cl);
                short8 pA8 = *(const short8*)(bA + 256 + cl);
                short8 fA8 = *(const short8*)(bA + 384 + cl);
                short8 kB8 = *(const short8*)(bB + cl);
                short8 vB8 = *(const short8*)(bB + 128 + cl);
                short8 pB8 = *(const short8*)(bB + 256 + cl);
                short8 fB8 = *(const short8*)(bB + 384 + cl);

                float sa = 0.f, sb = 0.f;
                #pragma unroll
                for (int i=0;i<8;i++){ sa += qA[i]*bf2f(kA8[i]); sb += qB[i]*bf2f(kB8[i]); }
                sa += __shfl_xor(sa,1); sb += __shfl_xor(sb,1);
                sa += __shfl_xor(sa,2); sb += __shfl_xor(sb,2);
                sa *= sc; sb *= sc;
                float ma = fmaxf(sa, __shfl_xor(sa,4)), mb = fmaxf(sb, __shfl_xor(sb,4));
                ma = fmaxf(ma, __shfl_xor(ma,8));       mb = fmaxf(mb, __shfl_xor(mb,8));
                float ea = expf(sa-ma), eb = expf(sb-mb);
                float da = ea, db = eb;
                da += __shfl_xor(da,4); db += __shfl_xor(db,4);
                da += __shfl_xor(da,8); db += __shfl_xor(db,8);
                float wa = vA ? (ea/da) : 0.f;
                float wb = vB ? (eb/db) : 0.f;
                float va_ = vA ? 1.f : 0.f, vb_ = vB ? 1.f : 0.f;
                #pragma unroll
                for (int i=0;i<8;i++){
                    aA[i] += wa  * bf2f(vA8[i]);   aB[i] += wb  * bf2f(vB8[i]);
                    sA[i] += va_ * bf2f(fA8[i]);   sB[i] += vb_ * bf2f(fB8[i]);
                    pA[i] += va_ * bf2f(pA8[i]);   pB[i] += vb_ * bf2f(pB8[i]);
                }
            }
            // combine the 4 edge-slot groups for both rows
            #pragma unroll
            for (int i=0;i<8;i++){
                aA[i] += __shfl_xor(aA[i],16); aA[i] += __shfl_xor(aA[i],32);
                sA[i] += __shfl_xor(sA[i],16); sA[i] += __shfl_xor(sA[i],32);
                pA[i] += __shfl_xor(pA[i],16); pA[i] += __shfl_xor(pA[i],32);
                aB[i] += __shfl_xor(aB[i],16); aB[i] += __shfl_xor(aB[i],32);
                sB[i] += __shfl_xor(sB[i],16); sB[i] += __shfl_xor(sB[i],32);
                pB[i] += __shfl_xor(pB[i],16); pB[i] += __shfl_xor(pB[i],32);
            }
            if (lane < 16){
                short8 sv, pv;
                #pragma unroll
                for (int i=0;i<8;i++){
                    AQM[rowA*128 + cl + i] = aA[i];
                    sv[i] = f2bf(sA[i]); pv[i] = f2bf(pA[i]);
                }
                ((short8*)Sbf)[C16(rowA, lane&15)] = sv;
                *(short8*)(PBbf + rowA*128 + cl) = pv;
                #pragma unroll
                for (int i=0;i<8;i++){
                    AQM[rowB*128 + cl + i] = aB[i];
                    sv[i] = f2bf(sB[i]); pv[i] = f2bf(pB[i]);
                }
                ((short8*)Sbf)[C16(rowB, lane&15)] = sv;
                *(short8*)(PBbf + rowB*128 + cl) = pv;
            }
        }
    }
    __syncthreads();                                       // B3

    // ---- reload FQ (a1 intact) + FS frags ----
    short8 FQ[2][4], FS[2][4];
    #pragma unroll
    for (int rt=0;rt<2;rt++)
        #pragma unroll
        for (int ks=0;ks<4;ks++){
            FQ[rt][ks] = ((const short8*)a1)[C16(rt*16+l15,(ks<<2)+lh)];
            FS[rt][ks] = ((const short8*)Sbf)[C16(rt*16+l15,(ks<<2)+lh)];
        }
    __syncthreads();                                       // B3b (a1 reads done before msgb writes)

    // ---- cross GEMMs ----
    f32x4 tt[2][2], cr[2][2];
    #pragma unroll
    for (int ci=0;ci<2;ci++){ tt[ci][0]=Z4; tt[ci][1]=Z4; cr[ci][0]=Z4; cr[ci][1]=Z4; }
    #pragma unroll 1
    for (int kk=0;kk<4;kk++){
        #pragma unroll
        for (int ci=0;ci<2;ci++){
            const int col = (2*w+ci)*16 + l15;
            const long wbase = (long)kk*32768 + (long)col*256;
            short8 Bia[4],Bja[4],Bib[4],Bjb[4];
            #pragma unroll
            for (int ks=0;ks<4;ks++){
                Bia[ks] = *(const short8*)(wCi + wbase + ks*32 + lh*8);
                Bja[ks] = *(const short8*)(wCj + wbase + ks*32 + lh*8);
                Bib[ks] = *(const short8*)(wCi + wbase + 128 + ks*32 + lh*8);
                Bjb[ks] = *(const short8*)(wCj + wbase + 128 + ks*32 + lh*8);
            }
            f32x4 ai[2],aj[2],sbi[2],sbj[2];
            #pragma unroll
            for (int rt=0;rt<2;rt++){ ai[rt]=Z4; aj[rt]=Z4; sbi[rt]=Z4; sbj[rt]=Z4; }
            #pragma unroll
            for (int ks=0;ks<4;ks++){
                #pragma unroll
                for (int rt=0;rt<2;rt++){
                    ai[rt]  = mfma16(FQ[rt][ks], Bia[ks], ai[rt]);
                    aj[rt]  = mfma16(FQ[rt][ks], Bja[ks], aj[rt]);
                    sbi[rt] = mfma16(FS[rt][ks], Bib[ks], sbi[rt]);
                    sbj[rt] = mfma16(FS[rt][ks], Bjb[ks], sbj[rt]);
                }
            }
            float ci_ = bci[kk*128+col], cj_ = bcj[kk*128+col];
            #pragma unroll
            for (int rt=0;rt<2;rt++){
                #pragma unroll
                for (int j=0;j<4;j++){
                    float AI = ai[rt][j]+ci_, AJ = aj[rt][j]+cj_;
                    tt[ci][rt][j] += AI*AJ;
                    cr[ci][rt][j] += AI*sbj[rt][j] + sbi[rt][j]*AJ;
                }
            }
        }
    }
    // ---- assemble msum, write msgb (over a1) ----
    short* msgb = a1;
    #pragma unroll
    for (int ci=0;ci<2;ci++){
        const int col = (2*w+ci)*16 + l15;
        #pragma unroll
        for (int rt=0;rt<2;rt++){
            #pragma unroll
            for (int j=0;j<4;j++){
                int row = rt*16+lj+j;
                float ms = AQM[row*128 + col]
                         + 0.25f*((float)degs[row]*tt[ci][rt][j] + cr[ci][rt][j]
                                  + bf2f(PBbf[row*128 + col]));
                msgb[(C16(row, col>>3)<<3) + (col&7)] = f2bf(ms);
            }
        }
    }
    __syncthreads();                                       // B4

    // ---- OUT GEMM -> yb (overlays qnl+AQM; both dead) ----
    short8 FM[2][4];
    #pragma unroll
    for (int rt=0;rt<2;rt++)
        #pragma unroll
        for (int ks=0;ks<4;ks++)
            FM[rt][ks] = ((const short8*)msgb)[C16(rt*16+l15,(ks<<2)+lh)];
    #pragma unroll
    for (int ci=0; ci<2; ci++){
        const int col = (2*w+ci)*16 + l15;
        f32x4 ao[2]; ao[0]=Z4; ao[1]=Z4;
        #pragma unroll
        for (int ks=0;ks<4;ks++){
            short8 b = *(const short8*)(wO + (long)col*128 + ks*32 + lh*8);
            ao[0]=mfma16(FM[0][ks],b,ao[0]);
            ao[1]=mfma16(FM[1][ks],b,ao[1]);
        }
        float ob = out_b[col];
        #pragma unroll
        for (int rt=0;rt<2;rt++)
            #pragma unroll
            for (int j=0;j<4;j++){
                int row = rt*16+lj+j;
                yb[(row<<7) + (col ^ (row&31))] = ao[rt][j] + (float)degs[row]*ob;
            }
    }
    __syncthreads();                                       // B5

    // ---- LN + exact gelu ----
    {
        const int row=tid>>3, cs=tid&7;
        const long n=n0+row;
        float v[16]; float sum=0.f, sq=0.f;
        #pragma unroll
        for (int i=0;i<16;i++){
            v[i]=yb[(row<<7)+((cs*16+i)^(row&31))];
            sum+=v[i]; sq+=v[i]*v[i];
        }
        #pragma unroll
        for (int m=1;m<8;m<<=1){ sum+=__shfl_xor(sum,m); sq+=__shfl_xor(sq,m); }
        float mean=sum*(1.0f/128.0f);
        float rstd=rsqrtf(sq*(1.0f/128.0f)-mean*mean+1e-5f);
        float o[16];
        #pragma unroll
        for (int i=0;i<16;i++){
            int c=cs*16+i;
            float y=(v[i]-mean)*rstd*g2[c]+b2[c];
            o[i]=0.5f*y*(1.0f+erff(y*0.70710678118f));
        }
        float* dst = outp + n*128 + cs*16;
        #pragma unroll
        for (int i=0;i<4;i++)
            ((float4*)dst)[i] = (float4){o[i*4],o[i*4+1],o[i*4+2],o[i*4+3]};
    }
}

extern "C" void kernel_launch(void* const* d_in, const int* in_sizes, int n_in,
                              void* d_out, int out_size, void* d_ws, size_t ws_size,
                              hipStream_t stream)
{
    const float* x      = (const float*)d_in[0];
    const int*   eidx   = (const int*)  d_in[1];
    const float* sp_w   = (const float*)d_in[2];
    const float* sp_b   = (const float*)d_in[3];
    const float* ln1_g  = (const float*)d_in[4];
    const float* ln1_b  = (const float*)d_in[5];
    const float* pg     = (const float*)d_in[6];
    const float* amp_w  = (const float*)d_in[7];
    const float* amp_b  = (const float*)d_in[8];
    const float* ph_w   = (const float*)d_in[9];
    const float* ph_b   = (const float*)d_in[10];
    const float* ent_w  = (const float*)d_in[11];
    const float* ent_b  = (const float*)d_in[12];
    const float* q_w    = (const float*)d_in[13];
    const float* q_b    = (const float*)d_in[14];
    const float* k_w    = (const float*)d_in[15];
    const float* k_b    = (const float*)d_in[16];
    const float* v_w    = (const float*)d_in[17];
    const float* v_b    = (const float*)d_in[18];
    const float* meas_w = (const float*)d_in[19];
    const float* meas_b = (const float*)d_in[20];
    const float* out_w  = (const float*)d_in[21];
    const float* out_b  = (const float*)d_in[22];
    const float* ln2_g  = (const float*)d_in[23];
    const float* ln2_b  = (const float*)d_in[24];

    char* wsb = (char*)d_ws;
    short* qfb  = (short*)(wsb + 0);               //  25,608,192
    short* knvp = (short*)(wsb + 25608192);        // 102,432,768
    short* wAll = (short*)(wsb + 128040960);       //     180,224
    short* wCi  = (short*)(wsb + 128221184);       //     262,144
    short* wCj  = (short*)(wsb + 128483328);       //     262,144
    float* bci  = (float*)(wsb + 128745472);       //       2,048
    float* bcj  = (float*)(wsb + 128747520);       //       2,048
    int* hist   = (int*)(wsb + 128749568);         //     401,408
    int* cnt    = (int*)(wsb + 129150976);         //     401,408
    int* scanv  = (int*)(wsb + 129552384);         //     401,408
    int* bsum   = (int*)(wsb + 129953792);         //       1,024
    int* boff   = (int*)(wsb + 129954816);         //       1,024
    int* sSrc   = (int*)(wsb + 129955840);         //   2,000,000 -> 131,955,840 total

    if (ws_size < 132000000ull) return;            // diagnostic guard

    short* wQ  = wAll;
    short* wK  = wAll + 16384;
    short* wV  = wAll + 32768;
    short* wO  = wAll + 49152;
    short* wSP = wAll + 65536;
    short* wA  = wAll + 81920;
    short* wP  = wAll + 86016;

    hipMemsetAsync(hist, 0, 401408, stream);
    hipMemsetAsync(cnt,  0, 401408, stream);

    prep_kernel<<<352, 256, 0, stream>>>(q_w, k_w, v_w, out_w, sp_w, amp_w, ph_w, wAll);
    combine_kernel<<<512, 256, 0, stream>>>(ent_w, meas_w, wCi, wCj);
    combine_bias_kernel<<<4, 256, 0, stream>>>(meas_w, ent_b, meas_b, bci, bcj);
    node_kernel<<<NNB, 512, 0, stream>>>(x, wSP, sp_b, ln1_g, ln1_b, pg,
                                         wA, amp_b, wP, ph_b, qfb);
    hist_kernel<<<(EE+255)/256, 256, 0, stream>>>(eidx, hist);
    scanA_kernel<<<196, 512, 0, stream>>>(hist, scanv, bsum);
    scanB_kernel<<<1, 256, 0, stream>>>(bsum, boff);
    scatter_kernel<<<(EE+255)/256, 256, 0, stream>>>(eidx, scanv, boff, cnt, sSrc);
    qkvpb_kernel<<<NNB, 512, 0, stream>>>(qfb, wK, k_b, wV, v_b, wCi, wCj, knvp);
    final_kernel<<<NFB, 256, 0, stream>>>(qfb, knvp, sSrc, hist, scanv, boff,
                                          wQ, q_b, wCi, wCj, bci, bcj, wO, out_b,
                                          ln2_g, ln2_b, (float*)d_out);
}